// Round 4
// baseline (480.558 us; speedup 1.0000x reference)
//
#include <hip/hip_runtime.h>
#include <hip/hip_bf16.h>
#include <math.h>

#define BLOCK 256
#define IMG 512
#define SW 88                   // staged bf16 stride (176 B: 16B-aligned b128 frags, 2-way banks)
#define NBLOCKS 3072            // 96 planes * 8 col-tiles * 4 row-chunks
#define NACC 128
#define N_TOTAL 25165824.0f

typedef float f32x4 __attribute__((ext_vector_type(4)));
typedef short s16x8 __attribute__((ext_vector_type(8)));
typedef short s16x4 __attribute__((ext_vector_type(4)));

struct WB { unsigned short b[11]; float c2; float k1; float k2; };
union FR  { unsigned int u[4]; s16x8 s; };
union FR2 { unsigned int u[2]; s16x4 s; };

// K=16 bf16 MFMA: builtin if present, else raw ISA (cdna4_isa.md §10 lists
// v_mfma_f32_16x16x16_bf16: A 2 regs, B 2 regs, C/D 4 regs).
#if __has_builtin(__builtin_amdgcn_mfma_f32_16x16x16bf16_1k)
#define MFMA16(A,B,C) __builtin_amdgcn_mfma_f32_16x16x16bf16_1k((A),(B),(C),0,0,0)
#else
__device__ __forceinline__ f32x4 mfma16_asm(s16x4 a, s16x4 b, f32x4 c) {
    f32x4 d;
    asm("v_mfma_f32_16x16x16_bf16 %0, %1, %2, %3" : "=v"(d) : "v"(a), "v"(b), "v"(c));
    return d;
}
#define MFMA16(A,B,C) mfma16_asm((A),(B),(C))
#endif

// lgkm-only workgroup barrier: __syncthreads() drains vmcnt(0) (WG release
// fence), which kills the 2-iteration global prefetch. Only s_q (DS/lgkm)
// crosses waves here. Memory-clobber fences on both sides pin DS ops.
#define WG_SYNC() do { \
    asm volatile("s_waitcnt lgkmcnt(0)" ::: "memory"); \
    __builtin_amdgcn_s_barrier(); \
    asm volatile("" ::: "memory"); \
} while (0)

__device__ __forceinline__ unsigned int pk2(float a, float b) {
    union { __hip_bfloat162 h; unsigned int u; } cv;
    cv.h = __float22bfloat162_rn(make_float2(a, b));
    return cv.u;
}

__device__ __forceinline__ void stage5(unsigned short (*sq)[16][SW],
                                       int r, int i, float4 xv, float4 yv) {
    *(uint2*)&sq[0][r][4*i] = make_uint2(pk2(xv.x,xv.y), pk2(xv.z,xv.w));
    *(uint2*)&sq[1][r][4*i] = make_uint2(pk2(yv.x,yv.y), pk2(yv.z,yv.w));
    *(uint2*)&sq[2][r][4*i] = make_uint2(pk2(xv.x*xv.x,xv.y*xv.y), pk2(xv.z*xv.z,xv.w*xv.w));
    *(uint2*)&sq[3][r][4*i] = make_uint2(pk2(yv.x*yv.x,yv.y*yv.y), pk2(yv.z*yv.z,yv.w*yv.w));
    *(uint2*)&sq[4][r][4*i] = make_uint2(pk2(xv.x*yv.x,xv.y*yv.y), pk2(xv.z*yv.z,xv.w*yv.w));
}

__device__ __forceinline__ void load_set(const float* __restrict__ P,
                                         const float* __restrict__ T,
                                         int R0, int step,
                                         int rA, int colA, bool okcA,
                                         bool hasB, int rB, int colB, bool okcB,
                                         float4& xA, float4& yA, float4& xB, float4& yB) {
    const int gr = R0 - 5 + 16 * step + rA;
    if (okcA && gr >= 0 && gr < IMG) {
        xA = *(const float4*)(P + ((size_t)gr << 9) + colA);
        yA = *(const float4*)(T + ((size_t)gr << 9) + colA);
    } else { xA = make_float4(0,0,0,0); yA = make_float4(0,0,0,0); }
    const int grB = R0 - 5 + 16 * step + rB;
    if (hasB && okcB && grB >= 0 && grB < IMG) {
        xB = *(const float4*)(P + ((size_t)grB << 9) + colB);
        yB = *(const float4*)(T + ((size_t)grB << 9) + colB);
    } else { xB = make_float4(0,0,0,0); yB = make_float4(0,0,0,0); }
}

__global__ __launch_bounds__(BLOCK, 7)
void ssim_tiled(const float* __restrict__ pred,
                const float* __restrict__ targ,
                float* __restrict__ accum, WB wb) {
    // Ring removed: V-pass B-fragments (16x16x16, k=quad*4+j) are exactly the
    // H-pass D-fragments (row=quad*4+reg) each lane already holds -> register
    // hand-off. LDS = s_q only: 14,080 B -> 7+ blocks/CU.
    __shared__ unsigned short s_q[5][16][SW];      // 14.1 KB

    const int tid = threadIdx.x;
    const int bx    = blockIdx.x;
    const int plane = bx >> 5;
    const int rem   = bx & 31;
    const int tx    = rem >> 2;
    const int ry    = rem & 3;
    const int C0    = tx * 64;
    const int R0    = ry * 128;

    const float* P = pred + (size_t)plane * (IMG * IMG);
    const float* T = targ + (size_t)plane * (IMG * IMG);

    const int w    = tid >> 6;
    const int lane = tid & 63;
    const int l15  = lane & 15;
    const int quad = lane >> 4;

    const int slotA = w * 80 + lane;
    const int rA = slotA / 20, iA = slotA % 20;
    const int colA = C0 - 8 + 4 * iA;
    const bool okcA = (colA >= 0) && (colA + 4 <= IMG);
    const bool hasB = (lane < 16);
    const int slotB = w * 80 + 64 + l15;
    const int rB = slotB / 20, iB = slotB % 20;
    const int colB = C0 - 8 + 4 * iB;
    const bool okcB = (colB >= 0) && (colB + 4 <= IMG);

    const float c2 = wb.c2, K1 = wb.k1, K2 = wb.k2;
    const f32x4 z = {0.f, 0.f, 0.f, 0.f};
    float lsum = 0.f;

    // ---- prologue: issue step-0 + step-1 global loads first (latency cover) ----
    float4 pxA, pyA, pxB, pyB;
    load_set(P, T, R0, 0, rA, colA, okcA, hasB, rB, colB, okcB, pxA, pyA, pxB, pyB);
    float4 sxA[2], syA[2], sxB[2], syB[2];
    load_set(P, T, R0, 1, rA, colA, okcA, hasB, rB, colB, okcB,
             sxA[1], syA[1], sxB[1], syB[1]);

    // ---- weight MFMA fragments built in registers ----
    // T[i] = ((i&31)<=10) ? b[i&31] : 0 ; pairT[i] = (T[i], T[(i+1)&63]).
    // bw (H, K=32 B-operand): word t = pairT[(8*quad - l15 - 3 + 2t)&63].
    // V split into two K=16 A-operands:
    //   A_lo[m][k] = g[k-m]      -> word t = pairT[(4*quad - l15 + 2t)&63]
    //   A_hi[m][k] = g[k+16-m]   -> word t = pairT[(4*quad - l15 + 16 + 2t)&63]
    // Index ranges checked: A_lo wraps negatives to T>=11 -> 0; straddle at
    // p=63 yields (0, b[0]) correctly. A_hi indices stay in [1,31] (no wrap),
    // T[11..31] = 0 covers the out-of-tap range.
    FR bw; FR2 awlo, awhi;
    {
        const int ti = lane & 31;
        int tv = 0;
#pragma unroll
        for (int k = 0; k < 11; ++k) tv = (ti == k) ? (int)wb.b[k] : tv;
        const int tnext = __shfl(tv, (lane + 1) & 63);
        const int pairT = (tv & 0xffff) | (tnext << 16);
        const int base_b = 8 * quad - l15 - 3;
        const int baseL  = 4 * quad - l15;
        const int baseH  = 4 * quad - l15 + 16;
#pragma unroll
        for (int t = 0; t < 4; ++t)
            bw.u[t] = (unsigned int)__shfl(pairT, (base_b + 2 * t) & 63);
#pragma unroll
        for (int t = 0; t < 2; ++t) {
            awlo.u[t] = (unsigned int)__shfl(pairT, (baseL + 2 * t) & 63);
            awhi.u[t] = (unsigned int)__shfl(pairT, (baseH + 2 * t) & 63);
        }
    }

    stage5(s_q, rA, iA, pxA, pyA);
    if (hasB) stage5(s_q, rB, iB, pxB, pyB);
    WG_SYNC();                     // s_q(step0) ready

    FR2 vb[2][5];                  // H-block bf16 fragments: [parity][matrix]

#pragma unroll
    for (int s = 0; s < 9; ++s) {
        // ---- issue loads for step s+2 (stays in flight across barriers now) ----
        if (s < 7) {
            load_set(P, T, R0, s + 2, rA, colA, okcA, hasB, rB, colB, okcB,
                     sxA[s & 1], syA[s & 1], sxB[s & 1], syB[s & 1]);
        }

        // ---- H: 5 b128 A-reads + 5 MFMA -> bf16 fragments in registers ----
        {
            FR a0, a1, a2, a3, a4;
            a0.s = *(const s16x8*)&s_q[0][l15][16*w + 8*quad];
            a1.s = *(const s16x8*)&s_q[1][l15][16*w + 8*quad];
            a2.s = *(const s16x8*)&s_q[2][l15][16*w + 8*quad];
            a3.s = *(const s16x8*)&s_q[3][l15][16*w + 8*quad];
            a4.s = *(const s16x8*)&s_q[4][l15][16*w + 8*quad];
            f32x4 d0 = __builtin_amdgcn_mfma_f32_16x16x32_bf16(a0.s, bw.s, z, 0, 0, 0);
            f32x4 d1 = __builtin_amdgcn_mfma_f32_16x16x32_bf16(a1.s, bw.s, z, 0, 0, 0);
            f32x4 d2 = __builtin_amdgcn_mfma_f32_16x16x32_bf16(a2.s, bw.s, z, 0, 0, 0);
            f32x4 d3 = __builtin_amdgcn_mfma_f32_16x16x32_bf16(a3.s, bw.s, z, 0, 0, 0);
            f32x4 d4 = __builtin_amdgcn_mfma_f32_16x16x32_bf16(a4.s, bw.s, z, 0, 0, 0);
            vb[s & 1][0].u[0] = pk2(d0[0], d0[1]); vb[s & 1][0].u[1] = pk2(d0[2], d0[3]);
            vb[s & 1][1].u[0] = pk2(d1[0], d1[1]); vb[s & 1][1].u[1] = pk2(d1[2], d1[3]);
            vb[s & 1][2].u[0] = pk2(d2[0], d2[1]); vb[s & 1][2].u[1] = pk2(d2[2], d2[3]);
            vb[s & 1][3].u[0] = pk2(d3[0], d3[1]); vb[s & 1][3].u[1] = pk2(d3[2], d3[3]);
            vb[s & 1][4].u[0] = pk2(d4[0], d4[1]); vb[s & 1][4].u[1] = pk2(d4[2], d4[3]);
        }

        WG_SYNC();                 // all H reads of s_q(step s) done

        // ---- stage step s+1 early; its DS writes drain under the V compute ----
        if (s < 8) {
            stage5(s_q, rA, iA, sxA[(s + 1) & 1], syA[(s + 1) & 1]);
            if (hasB) stage5(s_q, rB, iB, sxB[(s + 1) & 1], syB[(s + 1) & 1]);
        }

        // ---- V (register-only): out rows [R0+16t, +16) for t = s-1 ----
        if (s >= 1) {
            f32x4 acc5[5];
#pragma unroll
            for (int q = 0; q < 5; ++q)
                acc5[q] = MFMA16(awhi.s, vb[s & 1][q].s, z);
#pragma unroll
            for (int q = 0; q < 5; ++q)
                acc5[q] = MFMA16(awlo.s, vb[1 - (s & 1)][q].s, acc5[q]);
#pragma unroll
            for (int i = 0; i < 4; ++i) {
                const float u1  = acc5[0][i];
                const float u2  = acc5[1][i];
                const float m11 = u1 * u1;
                const float m22 = u2 * u2;
                const float m12 = u1 * u2;
                const float e11 = acc5[2][i] * c2;
                const float e22 = acc5[3][i] * c2;
                const float e12 = acc5[4][i] * c2;
                const float A = fmaf(2.f, m12, K1);
                const float B = fmaf(2.f, e12 - m12, K2);
                const float C = m11 + m22 + K1;
                const float D = (e11 + e22) - (m11 + m22) + K2;
                lsum = fmaf(A * B, __builtin_amdgcn_rcpf(C * D), lsum);
            }
        }

        if (s < 8) WG_SYNC();      // stage writes visible before next H reads
    }

#pragma unroll
    for (int off = 32; off > 0; off >>= 1) lsum += __shfl_down(lsum, off, 64);
    if (lane == 0) atomicAdd(&accum[(bx * 4 + w) & (NACC - 1)], lsum);
}

__global__ void ssim_finalize(const float* __restrict__ accum, float* __restrict__ out) {
    const int l = threadIdx.x;
    float v = accum[l] + accum[l + 64];
#pragma unroll
    for (int off = 32; off > 0; off >>= 1) v += __shfl_down(v, off, 64);
    if (l == 0) out[0] = 1.0f - v * (1.0f / N_TOTAL);
}

extern "C" void kernel_launch(void* const* d_in, const int* in_sizes, int n_in,
                              void* d_out, int out_size, void* d_ws, size_t ws_size,
                              hipStream_t stream) {
    const float* pred = (const float*)d_in[0];
    const float* targ = (const float*)d_in[1];
    float* out = (float*)d_out;
    float* ws  = (float*)d_ws;

    WB wb;
    {
        double gg[11], sum = 0.0;
        for (int k = 0; k < 11; ++k) {
            const double d = (double)(k - 5);
            gg[k] = exp(-d * d / 4.5);
            sum += gg[k];
        }
        double sbf = 0.0;
        for (int k = 0; k < 11; ++k) {
            union { float f; unsigned int u; } cv;
            cv.f = (float)(gg[k] / sum);
            const unsigned int r = (cv.u + 0x7fffu + ((cv.u >> 16) & 1u)) >> 16;
            wb.b[k] = (unsigned short)r;
            union { float f; unsigned int u; } bk;
            bk.u = r << 16;
            sbf += (double)bk.f;
        }
        const double s2 = sbf * sbf;       // acc = s2 * true value
        wb.c2 = (float)s2;
        wb.k1 = (float)(0.0001 * s2 * s2); // C1 in acc^2 units
        wb.k2 = (float)(0.0009 * s2 * s2); // C2 in acc^2 units
    }

    hipMemsetAsync(ws, 0, NACC * sizeof(float), stream);
    ssim_tiled<<<NBLOCKS, BLOCK, 0, stream>>>(pred, targ, ws, wb);
    ssim_finalize<<<1, 64, 0, stream>>>(ws, out);
}

// Round 5
// 307.449 us; speedup vs baseline: 1.5630x; 1.5630x over previous
//
#include <hip/hip_runtime.h>
#include <hip/hip_bf16.h>
#include <math.h>

#define BLOCK 256
#define IMG 512
#define SW 88                   // staged bf16 stride (176 B: 16B-aligned b128 frags, 2-way banks)
#define NBLOCKS 3072            // 96 planes * 8 col-tiles * 4 row-chunks
#define NACC 128
#define N_TOTAL 25165824.0f

typedef float f32x4 __attribute__((ext_vector_type(4)));
typedef short s16x8 __attribute__((ext_vector_type(8)));
typedef short s16x4 __attribute__((ext_vector_type(4)));

struct WB { unsigned short b[11]; float c2; float k1; float k2; };
union FR  { unsigned int u[4]; s16x8 s; };
union FR2 { unsigned int u[2]; s16x4 s; };

// K=16 bf16 MFMA (verified correct in R4: passed, absmax 0.0)
#if __has_builtin(__builtin_amdgcn_mfma_f32_16x16x16bf16_1k)
#define MFMA16(A,B,C) __builtin_amdgcn_mfma_f32_16x16x16bf16_1k((A),(B),(C),0,0,0)
#else
__device__ __forceinline__ f32x4 mfma16_asm(s16x4 a, s16x4 b, f32x4 c) {
    f32x4 d;
    asm("v_mfma_f32_16x16x16_bf16 %0, %1, %2, %3" : "=v"(d) : "v"(a), "v"(b), "v"(c));
    return d;
}
#define MFMA16(A,B,C) mfma16_asm((A),(B),(C))
#endif

// lgkm-only workgroup barrier: keeps prefetched global loads in flight
// across the barrier (no vmcnt(0) drain like __syncthreads()).
#define WG_SYNC() do { \
    asm volatile("s_waitcnt lgkmcnt(0)" ::: "memory"); \
    __builtin_amdgcn_s_barrier(); \
    asm volatile("" ::: "memory"); \
} while (0)

__device__ __forceinline__ unsigned int pk2(float a, float b) {
    union { __hip_bfloat162 h; unsigned int u; } cv;
    cv.h = __float22bfloat162_rn(make_float2(a, b));
    return cv.u;
}

// 4 staged matrices: 0:x  1:y  2:x^2+y^2  3:x*y
// (SSIM uses conv(x^2), conv(y^2) only via their SUM; conv is linear.)
__device__ __forceinline__ void stage4(unsigned short (*sq)[16][SW],
                                       int r, int i, float4 xv, float4 yv) {
    *(uint2*)&sq[0][r][4*i] = make_uint2(pk2(xv.x,xv.y), pk2(xv.z,xv.w));
    *(uint2*)&sq[1][r][4*i] = make_uint2(pk2(yv.x,yv.y), pk2(yv.z,yv.w));
    *(uint2*)&sq[2][r][4*i] = make_uint2(
        pk2(xv.x*xv.x + yv.x*yv.x, xv.y*xv.y + yv.y*yv.y),
        pk2(xv.z*xv.z + yv.z*yv.z, xv.w*xv.w + yv.w*yv.w));
    *(uint2*)&sq[3][r][4*i] = make_uint2(pk2(xv.x*yv.x, xv.y*yv.y),
                                         pk2(xv.z*yv.z, xv.w*yv.w));
}

__device__ __forceinline__ void load_set(const float* __restrict__ P,
                                         const float* __restrict__ T,
                                         int R0, int step,
                                         int rA, int colA, bool okcA,
                                         bool hasB, int rB, int colB, bool okcB,
                                         float4& xA, float4& yA, float4& xB, float4& yB) {
    const int gr = R0 - 5 + 16 * step + rA;
    if (okcA && gr >= 0 && gr < IMG) {
        xA = *(const float4*)(P + ((size_t)gr << 9) + colA);
        yA = *(const float4*)(T + ((size_t)gr << 9) + colA);
    } else { xA = make_float4(0,0,0,0); yA = make_float4(0,0,0,0); }
    const int grB = R0 - 5 + 16 * step + rB;
    if (hasB && okcB && grB >= 0 && grB < IMG) {
        xB = *(const float4*)(P + ((size_t)grB << 9) + colB);
        yB = *(const float4*)(T + ((size_t)grB << 9) + colB);
    } else { xB = make_float4(0,0,0,0); yB = make_float4(0,0,0,0); }
}

// ---- per-step phases; all indices compile-time (9 explicit expansions) ----
#define H_PHASE(CUR, QB)                                                     \
  do {                                                                       \
    FR a0_, a1_, a2_, a3_;                                                   \
    a0_.s = *(const s16x8*)&s_q[QB][0][l15][hoff];                           \
    a1_.s = *(const s16x8*)&s_q[QB][1][l15][hoff];                           \
    a2_.s = *(const s16x8*)&s_q[QB][2][l15][hoff];                           \
    a3_.s = *(const s16x8*)&s_q[QB][3][l15][hoff];                           \
    f32x4 d0_ = __builtin_amdgcn_mfma_f32_16x16x32_bf16(a0_.s, bw.s, z,0,0,0);\
    f32x4 d1_ = __builtin_amdgcn_mfma_f32_16x16x32_bf16(a1_.s, bw.s, z,0,0,0);\
    f32x4 d2_ = __builtin_amdgcn_mfma_f32_16x16x32_bf16(a2_.s, bw.s, z,0,0,0);\
    f32x4 d3_ = __builtin_amdgcn_mfma_f32_16x16x32_bf16(a3_.s, bw.s, z,0,0,0);\
    CUR[0].u[0]=pk2(d0_[0],d0_[1]); CUR[0].u[1]=pk2(d0_[2],d0_[3]);          \
    CUR[1].u[0]=pk2(d1_[0],d1_[1]); CUR[1].u[1]=pk2(d1_[2],d1_[3]);          \
    CUR[2].u[0]=pk2(d2_[0],d2_[1]); CUR[2].u[1]=pk2(d2_[2],d2_[3]);          \
    CUR[3].u[0]=pk2(d3_[0],d3_[1]); CUR[3].u[1]=pk2(d3_[2],d3_[3]);          \
  } while (0)

#define V_PHASE(CUR, PRV)                                                    \
  do {                                                                       \
    f32x4 c0_ = MFMA16(awhi.s, CUR[0].s, z);                                 \
    f32x4 c1_ = MFMA16(awhi.s, CUR[1].s, z);                                 \
    f32x4 c2_ = MFMA16(awhi.s, CUR[2].s, z);                                 \
    f32x4 c3_ = MFMA16(awhi.s, CUR[3].s, z);                                 \
    c0_ = MFMA16(awlo.s, PRV[0].s, c0_);                                     \
    c1_ = MFMA16(awlo.s, PRV[1].s, c1_);                                     \
    c2_ = MFMA16(awlo.s, PRV[2].s, c2_);                                     \
    c3_ = MFMA16(awlo.s, PRV[3].s, c3_);                                     \
    _Pragma("unroll")                                                        \
    for (int i = 0; i < 4; ++i) {                                            \
        const float u1   = c0_[i];                                           \
        const float u2   = c1_[i];                                           \
        const float m11  = u1 * u1;                                          \
        const float m22  = u2 * u2;                                          \
        const float m12  = u1 * u2;                                          \
        const float esum = c2_[i] * c2;      /* e11+e22 */                   \
        const float e12  = c3_[i] * c2;                                      \
        const float A_ = fmaf(2.f, m12, K1);                                 \
        const float B_ = fmaf(2.f, e12 - m12, K2);                           \
        const float C_ = m11 + m22 + K1;                                     \
        const float D_ = esum - (m11 + m22) + K2;                            \
        lsum = fmaf(A_ * B_, __builtin_amdgcn_rcpf(C_ * D_), lsum);          \
    }                                                                        \
  } while (0)

#define STEP(S, CUR, PRV, QB)                                                \
  do {                                                                       \
    if ((S) < 8)                                                             \
        load_set(P, T, R0, (S) + 1, rA, colA, okcA, hasB, rB, colB, okcB,    \
                 nxA, nyA, nxB, nyB);                                        \
    H_PHASE(CUR, QB);                                                        \
    if ((S) >= 1) V_PHASE(CUR, PRV);                                         \
    if ((S) < 8) {                                                           \
        stage4(s_q[1 - (QB)], rA, iA, nxA, nyA);                             \
        if (hasB) stage4(s_q[1 - (QB)], rB, iB, nxB, nyB);                   \
        WG_SYNC();                                                           \
    }                                                                        \
  } while (0)

__global__ __launch_bounds__(BLOCK, 6)
void ssim_tiled(const float* __restrict__ pred,
                const float* __restrict__ targ,
                float* __restrict__ accum, WB wb) {
    // double-buffered 4-matrix staging: 2*4*16*88*2 = 22,528 B
    __shared__ unsigned short s_q[2][4][16][SW];

    const int tid = threadIdx.x;
    const int bx    = blockIdx.x;
    const int plane = bx >> 5;
    const int rem   = bx & 31;
    const int tx    = rem >> 2;
    const int ry    = rem & 3;
    const int C0    = tx * 64;
    const int R0    = ry * 128;

    const float* P = pred + (size_t)plane * (IMG * IMG);
    const float* T = targ + (size_t)plane * (IMG * IMG);

    const int w    = tid >> 6;
    const int lane = tid & 63;
    const int l15  = lane & 15;
    const int quad = lane >> 4;
    const int hoff = 16 * w + 8 * quad;

    const int slotA = w * 80 + lane;
    const int rA = slotA / 20, iA = slotA % 20;
    const int colA = C0 - 8 + 4 * iA;
    const bool okcA = (colA >= 0) && (colA + 4 <= IMG);
    const bool hasB = (lane < 16);
    const int slotB = w * 80 + 64 + l15;
    const int rB = slotB / 20, iB = slotB % 20;
    const int colB = C0 - 8 + 4 * iB;
    const bool okcB = (colB >= 0) && (colB + 4 <= IMG);

    const float c2 = wb.c2, K1 = wb.k1, K2 = wb.k2;
    const f32x4 z = {0.f, 0.f, 0.f, 0.f};
    float lsum = 0.f;

    // ---- prologue: issue step-0 loads; build weights under their latency ----
    float4 nxA, nyA, nxB, nyB;
    load_set(P, T, R0, 0, rA, colA, okcA, hasB, rB, colB, okcB, nxA, nyA, nxB, nyB);

    // weight fragments in registers (verified in R4):
    // T[i] = ((i&31)<=10) ? b[i&31] : 0 ; pairT[i] = (T[i], T[(i+1)&63]).
    // bw   (H, K=32 B-op): word t = pairT[(8*quad - l15 - 3 + 2t)&63]
    // awlo (V, K=16 A-op): word t = pairT[(4*quad - l15      + 2t)&63]
    // awhi (V, K=16 A-op): word t = pairT[(4*quad - l15 + 16 + 2t)&63]
    FR bw; FR2 awlo, awhi;
    {
        const int ti = lane & 31;
        int tv = 0;
#pragma unroll
        for (int k = 0; k < 11; ++k) tv = (ti == k) ? (int)wb.b[k] : tv;
        const int tnext = __shfl(tv, (lane + 1) & 63);
        const int pairT = (tv & 0xffff) | (tnext << 16);
        const int base_b = 8 * quad - l15 - 3;
        const int baseL  = 4 * quad - l15;
        const int baseH  = 4 * quad - l15 + 16;
#pragma unroll
        for (int t = 0; t < 4; ++t)
            bw.u[t] = (unsigned int)__shfl(pairT, (base_b + 2 * t) & 63);
#pragma unroll
        for (int t = 0; t < 2; ++t) {
            awlo.u[t] = (unsigned int)__shfl(pairT, (baseL + 2 * t) & 63);
            awhi.u[t] = (unsigned int)__shfl(pairT, (baseH + 2 * t) & 63);
        }
    }

    stage4(s_q[0], rA, iA, nxA, nyA);
    if (hasB) stage4(s_q[0], rB, iB, nxB, nyB);
    WG_SYNC();                     // s_q[0] (step 0) ready

    FR2 vbE[4], vbO[4];            // H-block bf16 fragments, even/odd steps

    STEP(0, vbE, vbO, 0);
    STEP(1, vbO, vbE, 1);
    STEP(2, vbE, vbO, 0);
    STEP(3, vbO, vbE, 1);
    STEP(4, vbE, vbO, 0);
    STEP(5, vbO, vbE, 1);
    STEP(6, vbE, vbO, 0);
    STEP(7, vbO, vbE, 1);
    STEP(8, vbE, vbO, 0);

#pragma unroll
    for (int off = 32; off > 0; off >>= 1) lsum += __shfl_down(lsum, off, 64);
    if (lane == 0) atomicAdd(&accum[(bx * 4 + w) & (NACC - 1)], lsum);
}

__global__ void ssim_finalize(const float* __restrict__ accum, float* __restrict__ out) {
    const int l = threadIdx.x;
    float v = accum[l] + accum[l + 64];
#pragma unroll
    for (int off = 32; off > 0; off >>= 1) v += __shfl_down(v, off, 64);
    if (l == 0) out[0] = 1.0f - v * (1.0f / N_TOTAL);
}

extern "C" void kernel_launch(void* const* d_in, const int* in_sizes, int n_in,
                              void* d_out, int out_size, void* d_ws, size_t ws_size,
                              hipStream_t stream) {
    const float* pred = (const float*)d_in[0];
    const float* targ = (const float*)d_in[1];
    float* out = (float*)d_out;
    float* ws  = (float*)d_ws;

    WB wb;
    {
        double gg[11], sum = 0.0;
        for (int k = 0; k < 11; ++k) {
            const double d = (double)(k - 5);
            gg[k] = exp(-d * d / 4.5);
            sum += gg[k];
        }
        double sbf = 0.0;
        for (int k = 0; k < 11; ++k) {
            union { float f; unsigned int u; } cv;
            cv.f = (float)(gg[k] / sum);
            const unsigned int r = (cv.u + 0x7fffu + ((cv.u >> 16) & 1u)) >> 16;
            wb.b[k] = (unsigned short)r;
            union { float f; unsigned int u; } bk;
            bk.u = r << 16;
            sbf += (double)bk.f;
        }
        const double s2 = sbf * sbf;       // acc = s2 * true value
        wb.c2 = (float)s2;
        wb.k1 = (float)(0.0001 * s2 * s2); // C1 in acc^2 units
        wb.k2 = (float)(0.0009 * s2 * s2); // C2 in acc^2 units
    }

    hipMemsetAsync(ws, 0, NACC * sizeof(float), stream);
    ssim_tiled<<<NBLOCKS, BLOCK, 0, stream>>>(pred, targ, ws, wb);
    ssim_finalize<<<1, 64, 0, stream>>>(ws, out);
}

// Round 8
// 265.163 us; speedup vs baseline: 1.8123x; 1.1595x over previous
//
#include <hip/hip_runtime.h>
#include <hip/hip_bf16.h>
#include <math.h>

#define BLOCK 256
#define IMG 512
#define SW 88                   // staged bf16 stride (176 B: 16B-aligned b128 frags, 2-way banks)
#define NBLOCKS 3072            // 96 planes * 8 col-tiles * 4 row-chunks
#define NACC 128
#define N_TOTAL 25165824.0f

typedef float f32x4 __attribute__((ext_vector_type(4)));
typedef short s16x8 __attribute__((ext_vector_type(8)));
typedef short s16x4 __attribute__((ext_vector_type(4)));

struct WB { unsigned short b[11]; float c2; float k1; float k2; };
union FR  { unsigned int u[4]; s16x8 s; };
union FR2 { unsigned int u[2]; s16x4 s; };

// K=16 bf16 MFMA (verified correct in R4/R5: passed, absmax 0.0)
#if __has_builtin(__builtin_amdgcn_mfma_f32_16x16x16bf16_1k)
#define MFMA16(A,B,C) __builtin_amdgcn_mfma_f32_16x16x16bf16_1k((A),(B),(C),0,0,0)
#else
__device__ __forceinline__ f32x4 mfma16_asm(s16x4 a, s16x4 b, f32x4 c) {
    f32x4 d;
    asm("v_mfma_f32_16x16x16_bf16 %0, %1, %2, %3" : "=v"(d) : "v"(a), "v"(b), "v"(c));
    return d;
}
#define MFMA16(A,B,C) mfma16_asm((A),(B),(C))
#endif

// lgkm-only workgroup barrier: keeps prefetched global loads in flight
// across the barrier (no vmcnt(0) drain like __syncthreads()).
#define WG_SYNC() do { \
    asm volatile("s_waitcnt lgkmcnt(0)" ::: "memory"); \
    __builtin_amdgcn_s_barrier(); \
    asm volatile("" ::: "memory"); \
} while (0)

__device__ __forceinline__ unsigned int pk2(float a, float b) {
    union { __hip_bfloat162 h; unsigned int u; } cv;
    cv.h = __float22bfloat162_rn(make_float2(a, b));
    return cv.u;
}

// 4 staged matrices: 0:x  1:y  2:x^2+y^2  3:x*y
// (SSIM uses conv(x^2), conv(y^2) only via their SUM; conv is linear.)
__device__ __forceinline__ void stage4(unsigned short (*sq)[16][SW],
                                       int r, int i, float4 xv, float4 yv) {
    *(uint2*)&sq[0][r][4*i] = make_uint2(pk2(xv.x,xv.y), pk2(xv.z,xv.w));
    *(uint2*)&sq[1][r][4*i] = make_uint2(pk2(yv.x,yv.y), pk2(yv.z,yv.w));
    *(uint2*)&sq[2][r][4*i] = make_uint2(
        pk2(xv.x*xv.x + yv.x*yv.x, xv.y*xv.y + yv.y*yv.y),
        pk2(xv.z*xv.z + yv.z*yv.z, xv.w*xv.w + yv.w*yv.w));
    *(uint2*)&sq[3][r][4*i] = make_uint2(pk2(xv.x*yv.x, xv.y*yv.y),
                                         pk2(xv.z*yv.z, xv.w*yv.w));
}

__device__ __forceinline__ void load_set(const float* __restrict__ P,
                                         const float* __restrict__ T,
                                         int R0, int step,
                                         int rA, int colA, bool okcA,
                                         bool hasB, int rB, int colB, bool okcB,
                                         float4& xA, float4& yA, float4& xB, float4& yB) {
    const int gr = R0 - 5 + 16 * step + rA;
    if (okcA && gr >= 0 && gr < IMG) {
        xA = *(const float4*)(P + ((size_t)gr << 9) + colA);
        yA = *(const float4*)(T + ((size_t)gr << 9) + colA);
    } else { xA = make_float4(0,0,0,0); yA = make_float4(0,0,0,0); }
    const int grB = R0 - 5 + 16 * step + rB;
    if (hasB && okcB && grB >= 0 && grB < IMG) {
        xB = *(const float4*)(P + ((size_t)grB << 9) + colB);
        yB = *(const float4*)(T + ((size_t)grB << 9) + colB);
    } else { xB = make_float4(0,0,0,0); yB = make_float4(0,0,0,0); }
}

// ---- per-step phases; all indices compile-time (9 explicit expansions) ----
#define H_PHASE(CUR, QB)                                                     \
  do {                                                                       \
    FR a0_, a1_, a2_, a3_;                                                   \
    a0_.s = *(const s16x8*)&s_q[QB][0][l15][hoff];                           \
    a1_.s = *(const s16x8*)&s_q[QB][1][l15][hoff];                           \
    a2_.s = *(const s16x8*)&s_q[QB][2][l15][hoff];                           \
    a3_.s = *(const s16x8*)&s_q[QB][3][l15][hoff];                           \
    f32x4 d0_ = __builtin_amdgcn_mfma_f32_16x16x32_bf16(a0_.s, bw.s, z,0,0,0);\
    f32x4 d1_ = __builtin_amdgcn_mfma_f32_16x16x32_bf16(a1_.s, bw.s, z,0,0,0);\
    f32x4 d2_ = __builtin_amdgcn_mfma_f32_16x16x32_bf16(a2_.s, bw.s, z,0,0,0);\
    f32x4 d3_ = __builtin_amdgcn_mfma_f32_16x16x32_bf16(a3_.s, bw.s, z,0,0,0);\
    CUR[0].u[0]=pk2(d0_[0],d0_[1]); CUR[0].u[1]=pk2(d0_[2],d0_[3]);          \
    CUR[1].u[0]=pk2(d1_[0],d1_[1]); CUR[1].u[1]=pk2(d1_[2],d1_[3]);          \
    CUR[2].u[0]=pk2(d2_[0],d2_[1]); CUR[2].u[1]=pk2(d2_[2],d2_[3]);          \
    CUR[3].u[0]=pk2(d3_[0],d3_[1]); CUR[3].u[1]=pk2(d3_[2],d3_[3]);          \
  } while (0)

#define V_PHASE(CUR, PRV)                                                    \
  do {                                                                       \
    f32x4 c0_ = MFMA16(awhi.s, CUR[0].s, z);                                 \
    f32x4 c1_ = MFMA16(awhi.s, CUR[1].s, z);                                 \
    f32x4 c2_ = MFMA16(awhi.s, CUR[2].s, z);                                 \
    f32x4 c3_ = MFMA16(awhi.s, CUR[3].s, z);                                 \
    c0_ = MFMA16(awlo.s, PRV[0].s, c0_);                                     \
    c1_ = MFMA16(awlo.s, PRV[1].s, c1_);                                     \
    c2_ = MFMA16(awlo.s, PRV[2].s, c2_);                                     \
    c3_ = MFMA16(awlo.s, PRV[3].s, c3_);                                     \
    _Pragma("unroll")                                                        \
    for (int i = 0; i < 4; ++i) {                                            \
        const float u1   = c0_[i];                                           \
        const float u2   = c1_[i];                                           \
        const float m11  = u1 * u1;                                          \
        const float m22  = u2 * u2;                                          \
        const float m12  = u1 * u2;                                          \
        const float esum = c2_[i] * c2;      /* e11+e22 */                   \
        const float e12  = c3_[i] * c2;                                      \
        const float A_ = fmaf(2.f, m12, K1);                                 \
        const float B_ = fmaf(2.f, e12 - m12, K2);                           \
        const float C_ = m11 + m22 + K1;                                     \
        const float D_ = esum - (m11 + m22) + K2;                            \
        lsum = fmaf(A_ * B_, __builtin_amdgcn_rcpf(C_ * D_), lsum);          \
    }                                                                        \
  } while (0)

#define STEP(S, CUR, PRV, QB)                                                \
  do {                                                                       \
    if ((S) < 8)                                                             \
        load_set(P, T, R0, (S) + 1, rA, colA, okcA, hasB, rB, colB, okcB,    \
                 nxA, nyA, nxB, nyB);                                        \
    H_PHASE(CUR, QB);                                                        \
    if ((S) >= 1) V_PHASE(CUR, PRV);                                         \
    if ((S) < 8) {                                                           \
        stage4(s_q[1 - (QB)], rA, iA, nxA, nyA);                             \
        if (hasB) stage4(s_q[1 - (QB)], rB, iB, nxB, nyB);                   \
        WG_SYNC();                                                           \
    }                                                                        \
  } while (0)

__global__ __launch_bounds__(BLOCK, 4)
void ssim_tiled(const float* __restrict__ pred,
                const float* __restrict__ targ,
                float* __restrict__ accum, WB wb) {
    // double-buffered 4-matrix staging: 2*4*16*88*2 = 22,528 B
    __shared__ unsigned short s_q[2][4][16][SW];

    const int tid = threadIdx.x;
    const int bx    = blockIdx.x;
    const int plane = bx >> 5;
    const int rem   = bx & 31;
    const int tx    = rem >> 2;
    const int ry    = rem & 3;
    const int C0    = tx * 64;
    const int R0    = ry * 128;

    const float* P = pred + (size_t)plane * (IMG * IMG);
    const float* T = targ + (size_t)plane * (IMG * IMG);

    const int w    = tid >> 6;
    const int lane = tid & 63;
    const int l15  = lane & 15;
    const int quad = lane >> 4;
    const int hoff = 16 * w + 8 * quad;

    const int slotA = w * 80 + lane;
    const int rA = slotA / 20, iA = slotA % 20;
    const int colA = C0 - 8 + 4 * iA;
    const bool okcA = (colA >= 0) && (colA + 4 <= IMG);
    const bool hasB = (lane < 16);
    const int slotB = w * 80 + 64 + l15;
    const int rB = slotB / 20, iB = slotB % 20;
    const int colB = C0 - 8 + 4 * iB;
    const bool okcB = (colB >= 0) && (colB + 4 <= IMG);

    const float c2 = wb.c2, K1 = wb.k1, K2 = wb.k2;
    const f32x4 z = {0.f, 0.f, 0.f, 0.f};
    float lsum = 0.f;

    // ---- prologue: issue step-0 loads; build weights under their latency ----
    float4 nxA, nyA, nxB, nyB;
    load_set(P, T, R0, 0, rA, colA, okcA, hasB, rB, colB, okcB, nxA, nyA, nxB, nyB);

    // weight fragments in registers (verified in R4/R5):
    // T[i] = ((i&31)<=10) ? b[i&31] : 0 ; pairT[i] = (T[i], T[(i+1)&63]).
    // bw   (H, K=32 B-op): word t = pairT[(8*quad - l15 - 3 + 2t)&63]
    // awlo (V, K=16 A-op): word t = pairT[(4*quad - l15      + 2t)&63]
    // awhi (V, K=16 A-op): word t = pairT[(4*quad - l15 + 16 + 2t)&63]
    FR bw; FR2 awlo, awhi;
    {
        const int ti = lane & 31;
        int tv = 0;
#pragma unroll
        for (int k = 0; k < 11; ++k) tv = (ti == k) ? (int)wb.b[k] : tv;
        const int tnext = __shfl(tv, (lane + 1) & 63);
        const int pairT = (tv & 0xffff) | (tnext << 16);
        const int base_b = 8 * quad - l15 - 3;
        const int baseL  = 4 * quad - l15;
        const int baseH  = 4 * quad - l15 + 16;
#pragma unroll
        for (int t = 0; t < 4; ++t)
            bw.u[t] = (unsigned int)__shfl(pairT, (base_b + 2 * t) & 63);
#pragma unroll
        for (int t = 0; t < 2; ++t) {
            awlo.u[t] = (unsigned int)__shfl(pairT, (baseL + 2 * t) & 63);
            awhi.u[t] = (unsigned int)__shfl(pairT, (baseH + 2 * t) & 63);
        }
    }

    stage4(s_q[0], rA, iA, nxA, nyA);
    if (hasB) stage4(s_q[0], rB, iB, nxB, nyB);
    WG_SYNC();                     // s_q[0] (step 0) ready

    FR2 vbE[4], vbO[4];            // H-block bf16 fragments, even/odd steps

    STEP(0, vbE, vbO, 0);
    STEP(1, vbO, vbE, 1);
    STEP(2, vbE, vbO, 0);
    STEP(3, vbO, vbE, 1);
    STEP(4, vbE, vbO, 0);
    STEP(5, vbO, vbE, 1);
    STEP(6, vbE, vbO, 0);
    STEP(7, vbO, vbE, 1);
    STEP(8, vbE, vbO, 0);

#pragma unroll
    for (int off = 32; off > 0; off >>= 1) lsum += __shfl_down(lsum, off, 64);
    if (lane == 0) atomicAdd(&accum[(bx * 4 + w) & (NACC - 1)], lsum);
}

__global__ void ssim_finalize(const float* __restrict__ accum, float* __restrict__ out) {
    const int l = threadIdx.x;
    float v = accum[l] + accum[l + 64];
#pragma unroll
    for (int off = 32; off > 0; off >>= 1) v += __shfl_down(v, off, 64);
    if (l == 0) out[0] = 1.0f - v * (1.0f / N_TOTAL);
}

extern "C" void kernel_launch(void* const* d_in, const int* in_sizes, int n_in,
                              void* d_out, int out_size, void* d_ws, size_t ws_size,
                              hipStream_t stream) {
    const float* pred = (const float*)d_in[0];
    const float* targ = (const float*)d_in[1];
    float* out = (float*)d_out;
    float* ws  = (float*)d_ws;

    WB wb;
    {
        double gg[11], sum = 0.0;
        for (int k = 0; k < 11; ++k) {
            const double d = (double)(k - 5);
            gg[k] = exp(-d * d / 4.5);
            sum += gg[k];
        }
        double sbf = 0.0;
        for (int k = 0; k < 11; ++k) {
            union { float f; unsigned int u; } cv;
            cv.f = (float)(gg[k] / sum);
            const unsigned int r = (cv.u + 0x7fffu + ((cv.u >> 16) & 1u)) >> 16;
            wb.b[k] = (unsigned short)r;
            union { float f; unsigned int u; } bk;
            bk.u = r << 16;
            sbf += (double)bk.f;
        }
        const double s2 = sbf * sbf;       // acc = s2 * true value
        wb.c2 = (float)s2;
        wb.k1 = (float)(0.0001 * s2 * s2); // C1 in acc^2 units
        wb.k2 = (float)(0.0009 * s2 * s2); // C2 in acc^2 units
    }

    hipMemsetAsync(ws, 0, NACC * sizeof(float), stream);
    ssim_tiled<<<NBLOCKS, BLOCK, 0, stream>>>(pred, targ, ws, wb);
    ssim_finalize<<<1, 64, 0, stream>>>(ws, out);
}

// Round 10
// 250.005 us; speedup vs baseline: 1.9222x; 1.0606x over previous
//
#include <hip/hip_runtime.h>
#include <hip/hip_bf16.h>
#include <math.h>

#define BLOCK 256
#define IMG 512
#define SW 88                   // staged bf16 stride (176 B: 16B-aligned b128 frags, 2-way banks)
#define NBLOCKS 3072            // 96 planes * 8 col-tiles * 4 row-chunks
#define NACC 128
#define N_TOTAL 25165824.0f

typedef float f32x4 __attribute__((ext_vector_type(4)));
typedef short s16x8 __attribute__((ext_vector_type(8)));
typedef short s16x4 __attribute__((ext_vector_type(4)));

struct WB { unsigned short b[11]; float c2; float k1; float k2; };
union FR  { unsigned int u[4]; s16x8 s; };
union FR2 { unsigned int u[2]; s16x4 s; };

// K=16 bf16 MFMA (verified correct in R4/R5/R8: passed, absmax 0.0)
#if __has_builtin(__builtin_amdgcn_mfma_f32_16x16x16bf16_1k)
#define MFMA16(A,B,C) __builtin_amdgcn_mfma_f32_16x16x16bf16_1k((A),(B),(C),0,0,0)
#else
__device__ __forceinline__ f32x4 mfma16_asm(s16x4 a, s16x4 b, f32x4 c) {
    f32x4 d;
    asm("v_mfma_f32_16x16x16_bf16 %0, %1, %2, %3" : "=v"(d) : "v"(a), "v"(b), "v"(c));
    return d;
}
#define MFMA16(A,B,C) mfma16_asm((A),(B),(C))
#endif

// lgkm-only workgroup barrier: keeps prefetched global loads in flight
// across the barrier (no vmcnt(0) drain like __syncthreads()).
#define WG_SYNC() do { \
    asm volatile("s_waitcnt lgkmcnt(0)" ::: "memory"); \
    __builtin_amdgcn_s_barrier(); \
    asm volatile("" ::: "memory"); \
} while (0)

__device__ __forceinline__ unsigned int pk2(float a, float b) {
    union { __hip_bfloat162 h; unsigned int u; } cv;
    cv.h = __float22bfloat162_rn(make_float2(a, b));
    return cv.u;
}

// 4 staged matrices: 0:x  1:y  2:x^2+y^2  3:x*y
// (SSIM uses conv(x^2), conv(y^2) only via their SUM; conv is linear.)
__device__ __forceinline__ void stage4(unsigned short (*sq)[16][SW],
                                       int r, int i, float4 xv, float4 yv) {
    *(uint2*)&sq[0][r][4*i] = make_uint2(pk2(xv.x,xv.y), pk2(xv.z,xv.w));
    *(uint2*)&sq[1][r][4*i] = make_uint2(pk2(yv.x,yv.y), pk2(yv.z,yv.w));
    *(uint2*)&sq[2][r][4*i] = make_uint2(
        pk2(xv.x*xv.x + yv.x*yv.x, xv.y*xv.y + yv.y*yv.y),
        pk2(xv.z*xv.z + yv.z*yv.z, xv.w*xv.w + yv.w*yv.w));
    *(uint2*)&sq[3][r][4*i] = make_uint2(pk2(xv.x*yv.x, xv.y*yv.y),
                                         pk2(xv.z*yv.z, xv.w*yv.w));
}

__device__ __forceinline__ void load_set(const float* __restrict__ P,
                                         const float* __restrict__ T,
                                         int R0, int step,
                                         int rA, int colA, bool okcA,
                                         bool hasB, int rB, int colB, bool okcB,
                                         float4& xA, float4& yA, float4& xB, float4& yB) {
    const int gr = R0 - 5 + 16 * step + rA;
    if (okcA && gr >= 0 && gr < IMG) {
        xA = *(const float4*)(P + ((size_t)gr << 9) + colA);
        yA = *(const float4*)(T + ((size_t)gr << 9) + colA);
    } else { xA = make_float4(0,0,0,0); yA = make_float4(0,0,0,0); }
    const int grB = R0 - 5 + 16 * step + rB;
    if (hasB && okcB && grB >= 0 && grB < IMG) {
        xB = *(const float4*)(P + ((size_t)grB << 9) + colB);
        yB = *(const float4*)(T + ((size_t)grB << 9) + colB);
    } else { xB = make_float4(0,0,0,0); yB = make_float4(0,0,0,0); }
}

// ---- per-step phases; all indices compile-time (9 explicit expansions) ----
#define H_PHASE(CUR, QB)                                                     \
  do {                                                                       \
    FR a0_, a1_, a2_, a3_;                                                   \
    a0_.s = *(const s16x8*)&s_q[QB][0][l15][hoff];                           \
    a1_.s = *(const s16x8*)&s_q[QB][1][l15][hoff];                           \
    a2_.s = *(const s16x8*)&s_q[QB][2][l15][hoff];                           \
    a3_.s = *(const s16x8*)&s_q[QB][3][l15][hoff];                           \
    f32x4 d0_ = __builtin_amdgcn_mfma_f32_16x16x32_bf16(a0_.s, bw.s, z,0,0,0);\
    f32x4 d1_ = __builtin_amdgcn_mfma_f32_16x16x32_bf16(a1_.s, bw.s, z,0,0,0);\
    f32x4 d2_ = __builtin_amdgcn_mfma_f32_16x16x32_bf16(a2_.s, bw.s, z,0,0,0);\
    f32x4 d3_ = __builtin_amdgcn_mfma_f32_16x16x32_bf16(a3_.s, bw.s, z,0,0,0);\
    CUR[0].u[0]=pk2(d0_[0],d0_[1]); CUR[0].u[1]=pk2(d0_[2],d0_[3]);          \
    CUR[1].u[0]=pk2(d1_[0],d1_[1]); CUR[1].u[1]=pk2(d1_[2],d1_[3]);          \
    CUR[2].u[0]=pk2(d2_[0],d2_[1]); CUR[2].u[1]=pk2(d2_[2],d2_[3]);          \
    CUR[3].u[0]=pk2(d3_[0],d3_[1]); CUR[3].u[1]=pk2(d3_[2],d3_[3]);          \
  } while (0)

#define V_PHASE(CUR, PRV)                                                    \
  do {                                                                       \
    f32x4 c0_ = MFMA16(awhi.s, CUR[0].s, z);                                 \
    f32x4 c1_ = MFMA16(awhi.s, CUR[1].s, z);                                 \
    f32x4 c2_ = MFMA16(awhi.s, CUR[2].s, z);                                 \
    f32x4 c3_ = MFMA16(awhi.s, CUR[3].s, z);                                 \
    c0_ = MFMA16(awlo.s, PRV[0].s, c0_);                                     \
    c1_ = MFMA16(awlo.s, PRV[1].s, c1_);                                     \
    c2_ = MFMA16(awlo.s, PRV[2].s, c2_);                                     \
    c3_ = MFMA16(awlo.s, PRV[3].s, c3_);                                     \
    _Pragma("unroll")                                                        \
    for (int i = 0; i < 4; ++i) {                                            \
        const float u1   = c0_[i];                                           \
        const float u2   = c1_[i];                                           \
        const float m11  = u1 * u1;                                          \
        const float m22  = u2 * u2;                                          \
        const float m12  = u1 * u2;                                          \
        const float esum = c2_[i] * c2;      /* e11+e22 */                   \
        const float e12  = c3_[i] * c2;                                      \
        const float A_ = fmaf(2.f, m12, K1);                                 \
        const float B_ = fmaf(2.f, e12 - m12, K2);                           \
        const float C_ = m11 + m22 + K1;                                     \
        const float D_ = esum - (m11 + m22) + K2;                            \
        lsum = fmaf(A_ * B_, __builtin_amdgcn_rcpf(C_ * D_), lsum);          \
    }                                                                        \
  } while (0)

#define STEP(S, CUR, PRV, QB)                                                \
  do {                                                                       \
    if ((S) < 8)                                                             \
        load_set(P, T, R0, (S) + 1, rA, colA, okcA, hasB, rB, colB, okcB,    \
                 nxA, nyA, nxB, nyB);                                        \
    H_PHASE(CUR, QB);                                                        \
    if ((S) >= 1) V_PHASE(CUR, PRV);                                         \
    if ((S) < 8) {                                                           \
        stage4(s_q[1 - (QB)], rA, iA, nxA, nyA);                             \
        if (hasB) stage4(s_q[1 - (QB)], rB, iB, nxB, nyB);                   \
        WG_SYNC();                                                           \
    }                                                                        \
  } while (0)

__global__ __launch_bounds__(BLOCK, 3)
void ssim_tiled(const float* __restrict__ pred,
                const float* __restrict__ targ,
                float* __restrict__ accum, WB wb) {
    // double-buffered 4-matrix staging: 2*4*16*88*2 = 22,528 B
    __shared__ unsigned short s_q[2][4][16][SW];

    const int tid = threadIdx.x;
    const int bx    = blockIdx.x;
    const int plane = bx >> 5;
    const int rem   = bx & 31;
    const int tx    = rem >> 2;
    const int ry    = rem & 3;
    const int C0    = tx * 64;
    const int R0    = ry * 128;

    const float* P = pred + (size_t)plane * (IMG * IMG);
    const float* T = targ + (size_t)plane * (IMG * IMG);

    const int w    = tid >> 6;
    const int lane = tid & 63;
    const int l15  = lane & 15;
    const int quad = lane >> 4;
    const int hoff = 16 * w + 8 * quad;

    const int slotA = w * 80 + lane;
    const int rA = slotA / 20, iA = slotA % 20;
    const int colA = C0 - 8 + 4 * iA;
    const bool okcA = (colA >= 0) && (colA + 4 <= IMG);
    const bool hasB = (lane < 16);
    const int slotB = w * 80 + 64 + l15;
    const int rB = slotB / 20, iB = slotB % 20;
    const int colB = C0 - 8 + 4 * iB;
    const bool okcB = (colB >= 0) && (colB + 4 <= IMG);

    const float c2 = wb.c2, K1 = wb.k1, K2 = wb.k2;
    const f32x4 z = {0.f, 0.f, 0.f, 0.f};
    float lsum = 0.f;

    // ---- prologue: issue step-0 loads; build weights under their latency ----
    float4 nxA, nyA, nxB, nyB;
    load_set(P, T, R0, 0, rA, colA, okcA, hasB, rB, colB, okcB, nxA, nyA, nxB, nyB);

    // weight fragments in registers (verified in R4/R5/R8):
    // T[i] = ((i&31)<=10) ? b[i&31] : 0 ; pairT[i] = (T[i], T[(i+1)&63]).
    // bw   (H, K=32 B-op): word t = pairT[(8*quad - l15 - 3 + 2t)&63]
    // awlo (V, K=16 A-op): word t = pairT[(4*quad - l15      + 2t)&63]
    // awhi (V, K=16 A-op): word t = pairT[(4*quad - l15 + 16 + 2t)&63]
    FR bw; FR2 awlo, awhi;
    {
        const int ti = lane & 31;
        int tv = 0;
#pragma unroll
        for (int k = 0; k < 11; ++k) tv = (ti == k) ? (int)wb.b[k] : tv;
        const int tnext = __shfl(tv, (lane + 1) & 63);
        const int pairT = (tv & 0xffff) | (tnext << 16);
        const int base_b = 8 * quad - l15 - 3;
        const int baseL  = 4 * quad - l15;
        const int baseH  = 4 * quad - l15 + 16;
#pragma unroll
        for (int t = 0; t < 4; ++t)
            bw.u[t] = (unsigned int)__shfl(pairT, (base_b + 2 * t) & 63);
#pragma unroll
        for (int t = 0; t < 2; ++t) {
            awlo.u[t] = (unsigned int)__shfl(pairT, (baseL + 2 * t) & 63);
            awhi.u[t] = (unsigned int)__shfl(pairT, (baseH + 2 * t) & 63);
        }
    }

    stage4(s_q[0], rA, iA, nxA, nyA);
    if (hasB) stage4(s_q[0], rB, iB, nxB, nyB);
    WG_SYNC();                     // s_q[0] (step 0) ready

    FR2 vbE[4], vbO[4];            // H-block bf16 fragments, even/odd steps

    STEP(0, vbE, vbO, 0);
    STEP(1, vbO, vbE, 1);
    STEP(2, vbE, vbO, 0);
    STEP(3, vbO, vbE, 1);
    STEP(4, vbE, vbO, 0);
    STEP(5, vbO, vbE, 1);
    STEP(6, vbE, vbO, 0);
    STEP(7, vbO, vbE, 1);
    STEP(8, vbE, vbO, 0);

#pragma unroll
    for (int off = 32; off > 0; off >>= 1) lsum += __shfl_down(lsum, off, 64);
    if (lane == 0) atomicAdd(&accum[(bx * 4 + w) & (NACC - 1)], lsum);
}

__global__ void ssim_finalize(const float* __restrict__ accum, float* __restrict__ out) {
    const int l = threadIdx.x;
    float v = accum[l] + accum[l + 64];
#pragma unroll
    for (int off = 32; off > 0; off >>= 1) v += __shfl_down(v, off, 64);
    if (l == 0) out[0] = 1.0f - v * (1.0f / N_TOTAL);
}

extern "C" void kernel_launch(void* const* d_in, const int* in_sizes, int n_in,
                              void* d_out, int out_size, void* d_ws, size_t ws_size,
                              hipStream_t stream) {
    const float* pred = (const float*)d_in[0];
    const float* targ = (const float*)d_in[1];
    float* out = (float*)d_out;
    float* ws  = (float*)d_ws;

    WB wb;
    {
        double gg[11], sum = 0.0;
        for (int k = 0; k < 11; ++k) {
            const double d = (double)(k - 5);
            gg[k] = exp(-d * d / 4.5);
            sum += gg[k];
        }
        double sbf = 0.0;
        for (int k = 0; k < 11; ++k) {
            union { float f; unsigned int u; } cv;
            cv.f = (float)(gg[k] / sum);
            const unsigned int r = (cv.u + 0x7fffu + ((cv.u >> 16) & 1u)) >> 16;
            wb.b[k] = (unsigned short)r;
            union { float f; unsigned int u; } bk;
            bk.u = r << 16;
            sbf += (double)bk.f;
        }
        const double s2 = sbf * sbf;       // acc = s2 * true value
        wb.c2 = (float)s2;
        wb.k1 = (float)(0.0001 * s2 * s2); // C1 in acc^2 units
        wb.k2 = (float)(0.0009 * s2 * s2); // C2 in acc^2 units
    }

    hipMemsetAsync(ws, 0, NACC * sizeof(float), stream);
    ssim_tiled<<<NBLOCKS, BLOCK, 0, stream>>>(pred, targ, ws, wb);
    ssim_finalize<<<1, 64, 0, stream>>>(ws, out);
}

// Round 11
// 241.425 us; speedup vs baseline: 1.9905x; 1.0355x over previous
//
#include <hip/hip_runtime.h>
#include <hip/hip_bf16.h>
#include <math.h>

#define BLOCK 256
#define IMG 512
#define SW 88                   // staged bf16 stride (176 B: 16B-aligned b128 frags, 2-way banks)
#define NBLOCKS 3072            // 96 planes * 8 col-tiles * 4 row-chunks
#define NACC 128
#define N_TOTAL 25165824.0f

typedef float f32x4 __attribute__((ext_vector_type(4)));
typedef short s16x8 __attribute__((ext_vector_type(8)));
typedef short s16x4 __attribute__((ext_vector_type(4)));

struct WB { unsigned short b[11]; float c2; float k1; float k2; };
union FR  { unsigned int u[4]; s16x8 s; };
union FR2 { unsigned int u[2]; s16x4 s; };

// K=16 bf16 MFMA (verified correct in R4/R5/R8/R10: passed, absmax 0.0)
#if __has_builtin(__builtin_amdgcn_mfma_f32_16x16x16bf16_1k)
#define MFMA16(A,B,C) __builtin_amdgcn_mfma_f32_16x16x16bf16_1k((A),(B),(C),0,0,0)
#else
__device__ __forceinline__ f32x4 mfma16_asm(s16x4 a, s16x4 b, f32x4 c) {
    f32x4 d;
    asm("v_mfma_f32_16x16x16_bf16 %0, %1, %2, %3" : "=v"(d) : "v"(a), "v"(b), "v"(c));
    return d;
}
#define MFMA16(A,B,C) mfma16_asm((A),(B),(C))
#endif

// lgkm-only workgroup barrier: keeps prefetched global loads in flight
// across the barrier (no vmcnt(0) drain like __syncthreads()).
#define WG_SYNC() do { \
    asm volatile("s_waitcnt lgkmcnt(0)" ::: "memory"); \
    __builtin_amdgcn_s_barrier(); \
    asm volatile("" ::: "memory"); \
} while (0)

__device__ __forceinline__ unsigned int pk2(float a, float b) {
    union { __hip_bfloat162 h; unsigned int u; } cv;
    cv.h = __float22bfloat162_rn(make_float2(a, b));
    return cv.u;
}

// 4 staged matrices: 0:x  1:y  2:x^2+y^2  3:x*y
// (SSIM uses conv(x^2), conv(y^2) only via their SUM; conv is linear.)
__device__ __forceinline__ void stage4(unsigned short (*sq)[16][SW],
                                       int r, int i, float4 xv, float4 yv) {
    *(uint2*)&sq[0][r][4*i] = make_uint2(pk2(xv.x,xv.y), pk2(xv.z,xv.w));
    *(uint2*)&sq[1][r][4*i] = make_uint2(pk2(yv.x,yv.y), pk2(yv.z,yv.w));
    *(uint2*)&sq[2][r][4*i] = make_uint2(
        pk2(xv.x*xv.x + yv.x*yv.x, xv.y*xv.y + yv.y*yv.y),
        pk2(xv.z*xv.z + yv.z*yv.z, xv.w*xv.w + yv.w*yv.w));
    *(uint2*)&sq[3][r][4*i] = make_uint2(pk2(xv.x*yv.x, xv.y*yv.y),
                                         pk2(xv.z*yv.z, xv.w*yv.w));
}

__device__ __forceinline__ void load_set(const float* __restrict__ P,
                                         const float* __restrict__ T,
                                         int R0, int step,
                                         int rA, int colA, bool okcA,
                                         bool hasB, int rB, int colB, bool okcB,
                                         float4& xA, float4& yA, float4& xB, float4& yB) {
    const int gr = R0 - 5 + 16 * step + rA;
    if (okcA && gr >= 0 && gr < IMG) {
        xA = *(const float4*)(P + ((size_t)gr << 9) + colA);
        yA = *(const float4*)(T + ((size_t)gr << 9) + colA);
    } else { xA = make_float4(0,0,0,0); yA = make_float4(0,0,0,0); }
    const int grB = R0 - 5 + 16 * step + rB;
    if (hasB && okcB && grB >= 0 && grB < IMG) {
        xB = *(const float4*)(P + ((size_t)grB << 9) + colB);
        yB = *(const float4*)(T + ((size_t)grB << 9) + colB);
    } else { xB = make_float4(0,0,0,0); yB = make_float4(0,0,0,0); }
}

// ---- per-step phases; all indices compile-time (9 explicit expansions) ----
#define H_PHASE(CUR, QB)                                                     \
  do {                                                                       \
    FR a0_, a1_, a2_, a3_;                                                   \
    a0_.s = *(const s16x8*)&s_q[QB][0][l15][hoff];                           \
    a1_.s = *(const s16x8*)&s_q[QB][1][l15][hoff];                           \
    a2_.s = *(const s16x8*)&s_q[QB][2][l15][hoff];                           \
    a3_.s = *(const s16x8*)&s_q[QB][3][l15][hoff];                           \
    f32x4 d0_ = __builtin_amdgcn_mfma_f32_16x16x32_bf16(a0_.s, bw.s, z,0,0,0);\
    f32x4 d1_ = __builtin_amdgcn_mfma_f32_16x16x32_bf16(a1_.s, bw.s, z,0,0,0);\
    f32x4 d2_ = __builtin_amdgcn_mfma_f32_16x16x32_bf16(a2_.s, bw.s, z,0,0,0);\
    f32x4 d3_ = __builtin_amdgcn_mfma_f32_16x16x32_bf16(a3_.s, bw.s, z,0,0,0);\
    CUR[0].u[0]=pk2(d0_[0],d0_[1]); CUR[0].u[1]=pk2(d0_[2],d0_[3]);          \
    CUR[1].u[0]=pk2(d1_[0],d1_[1]); CUR[1].u[1]=pk2(d1_[2],d1_[3]);          \
    CUR[2].u[0]=pk2(d2_[0],d2_[1]); CUR[2].u[1]=pk2(d2_[2],d2_[3]);          \
    CUR[3].u[0]=pk2(d3_[0],d3_[1]); CUR[3].u[1]=pk2(d3_[2],d3_[3]);          \
  } while (0)

#define V_PHASE(CUR, PRV)                                                    \
  do {                                                                       \
    f32x4 c0_ = MFMA16(awhi.s, CUR[0].s, z);                                 \
    f32x4 c1_ = MFMA16(awhi.s, CUR[1].s, z);                                 \
    f32x4 c2_ = MFMA16(awhi.s, CUR[2].s, z);                                 \
    f32x4 c3_ = MFMA16(awhi.s, CUR[3].s, z);                                 \
    c0_ = MFMA16(awlo.s, PRV[0].s, c0_);                                     \
    c1_ = MFMA16(awlo.s, PRV[1].s, c1_);                                     \
    c2_ = MFMA16(awlo.s, PRV[2].s, c2_);                                     \
    c3_ = MFMA16(awlo.s, PRV[3].s, c3_);                                     \
    _Pragma("unroll")                                                        \
    for (int i = 0; i < 4; ++i) {                                            \
        const float u1   = c0_[i];                                           \
        const float u2   = c1_[i];                                           \
        const float m11  = u1 * u1;                                          \
        const float m22  = u2 * u2;                                          \
        const float m12  = u1 * u2;                                          \
        const float esum = c2_[i] * c2;      /* e11+e22 */                   \
        const float e12  = c3_[i] * c2;                                      \
        const float A_ = fmaf(2.f, m12, K1);                                 \
        const float B_ = fmaf(2.f, e12 - m12, K2);                           \
        const float C_ = m11 + m22 + K1;                                     \
        const float D_ = esum - (m11 + m22) + K2;                            \
        lsum = fmaf(A_ * B_, __builtin_amdgcn_rcpf(C_ * D_), lsum);          \
    }                                                                        \
  } while (0)

// 2-deep prefetch: STEP(S) issues loads for step S+2 into the L-set and
// stages step S+1 from the T-set (loaded at STEP(S-1); ~1.5 steps of cover
// for the HBM latency at the stage4 vmcnt wait — the R2-proven depth).
#define STEP(S, CUR, PRV, QB, LXA, LYA, LXB, LYB, TXA, TYA, TXB, TYB)        \
  do {                                                                       \
    if ((S) < 7)                                                             \
        load_set(P, T, R0, (S) + 2, rA, colA, okcA, hasB, rB, colB, okcB,    \
                 LXA, LYA, LXB, LYB);                                        \
    H_PHASE(CUR, QB);                                                        \
    if ((S) >= 1) V_PHASE(CUR, PRV);                                         \
    if ((S) < 8) {                                                           \
        stage4(s_q[1 - (QB)], rA, iA, TXA, TYA);                             \
        if (hasB) stage4(s_q[1 - (QB)], rB, iB, TXB, TYB);                   \
        WG_SYNC();                                                           \
    }                                                                        \
  } while (0)

__global__ __launch_bounds__(BLOCK, 3)
void ssim_tiled(const float* __restrict__ pred,
                const float* __restrict__ targ,
                float* __restrict__ accum, WB wb) {
    // double-buffered 4-matrix staging: 2*4*16*88*2 = 22,528 B
    __shared__ unsigned short s_q[2][4][16][SW];

    const int tid = threadIdx.x;
    const int bx    = blockIdx.x;
    const int plane = bx >> 5;
    const int rem   = bx & 31;
    const int tx    = rem >> 2;
    const int ry    = rem & 3;
    const int C0    = tx * 64;
    const int R0    = ry * 128;

    const float* P = pred + (size_t)plane * (IMG * IMG);
    const float* T = targ + (size_t)plane * (IMG * IMG);

    const int w    = tid >> 6;
    const int lane = tid & 63;
    const int l15  = lane & 15;
    const int quad = lane >> 4;
    const int hoff = 16 * w + 8 * quad;

    const int slotA = w * 80 + lane;
    const int rA = slotA / 20, iA = slotA % 20;
    const int colA = C0 - 8 + 4 * iA;
    const bool okcA = (colA >= 0) && (colA + 4 <= IMG);
    const bool hasB = (lane < 16);
    const int slotB = w * 80 + 64 + l15;
    const int rB = slotB / 20, iB = slotB % 20;
    const int colB = C0 - 8 + 4 * iB;
    const bool okcB = (colB >= 0) && (colB + 4 <= IMG);

    const float c2 = wb.c2, K1 = wb.k1, K2 = wb.k2;
    const f32x4 z = {0.f, 0.f, 0.f, 0.f};
    float lsum = 0.f;

    // ---- prologue: issue step-0 AND step-1 loads first (latency cover) ----
    float4 aXA0, aYA0, aXB0, aYB0;     // prefetch buffer 0
    float4 aXA1, aYA1, aXB1, aYB1;     // prefetch buffer 1
    load_set(P, T, R0, 0, rA, colA, okcA, hasB, rB, colB, okcB,
             aXA0, aYA0, aXB0, aYB0);
    load_set(P, T, R0, 1, rA, colA, okcA, hasB, rB, colB, okcB,
             aXA1, aYA1, aXB1, aYB1);

    // weight fragments in registers (verified in R4/R5/R8/R10):
    // T[i] = ((i&31)<=10) ? b[i&31] : 0 ; pairT[i] = (T[i], T[(i+1)&63]).
    // bw   (H, K=32 B-op): word t = pairT[(8*quad - l15 - 3 + 2t)&63]
    // awlo (V, K=16 A-op): word t = pairT[(4*quad - l15      + 2t)&63]
    // awhi (V, K=16 A-op): word t = pairT[(4*quad - l15 + 16 + 2t)&63]
    FR bw; FR2 awlo, awhi;
    {
        const int ti = lane & 31;
        int tv = 0;
#pragma unroll
        for (int k = 0; k < 11; ++k) tv = (ti == k) ? (int)wb.b[k] : tv;
        const int tnext = __shfl(tv, (lane + 1) & 63);
        const int pairT = (tv & 0xffff) | (tnext << 16);
        const int base_b = 8 * quad - l15 - 3;
        const int baseL  = 4 * quad - l15;
        const int baseH  = 4 * quad - l15 + 16;
#pragma unroll
        for (int t = 0; t < 4; ++t)
            bw.u[t] = (unsigned int)__shfl(pairT, (base_b + 2 * t) & 63);
#pragma unroll
        for (int t = 0; t < 2; ++t) {
            awlo.u[t] = (unsigned int)__shfl(pairT, (baseL + 2 * t) & 63);
            awhi.u[t] = (unsigned int)__shfl(pairT, (baseH + 2 * t) & 63);
        }
    }

    // stage step 0 (buffer 0 is then free for STEP(0)'s load of step 2)
    stage4(s_q[0], rA, iA, aXA0, aYA0);
    if (hasB) stage4(s_q[0], rB, iB, aXB0, aYB0);
    WG_SYNC();                     // s_q[0] (step 0) ready

    FR2 vbE[4], vbO[4];            // H-block bf16 fragments, even/odd steps

    // buffer rotation: STEP(S) loads step S+2 into buf[S&1], stages step S+1
    // from buf[(S+1)&1] (prologue put step 1 in buf1).
    STEP(0, vbE, vbO, 0, aXA0, aYA0, aXB0, aYB0, aXA1, aYA1, aXB1, aYB1);
    STEP(1, vbO, vbE, 1, aXA1, aYA1, aXB1, aYB1, aXA0, aYA0, aXB0, aYB0);
    STEP(2, vbE, vbO, 0, aXA0, aYA0, aXB0, aYB0, aXA1, aYA1, aXB1, aYB1);
    STEP(3, vbO, vbE, 1, aXA1, aYA1, aXB1, aYB1, aXA0, aYA0, aXB0, aYB0);
    STEP(4, vbE, vbO, 0, aXA0, aYA0, aXB0, aYB0, aXA1, aYA1, aXB1, aYB1);
    STEP(5, vbO, vbE, 1, aXA1, aYA1, aXB1, aYB1, aXA0, aYA0, aXB0, aYB0);
    STEP(6, vbE, vbO, 0, aXA0, aYA0, aXB0, aYB0, aXA1, aYA1, aXB1, aYB1);
    STEP(7, vbO, vbE, 1, aXA1, aYA1, aXB1, aYB1, aXA0, aYA0, aXB0, aYB0);
    STEP(8, vbE, vbO, 0, aXA0, aYA0, aXB0, aYB0, aXA1, aYA1, aXB1, aYB1);

#pragma unroll
    for (int off = 32; off > 0; off >>= 1) lsum += __shfl_down(lsum, off, 64);
    if (lane == 0) atomicAdd(&accum[(bx * 4 + w) & (NACC - 1)], lsum);
}

__global__ void ssim_finalize(const float* __restrict__ accum, float* __restrict__ out) {
    const int l = threadIdx.x;
    float v = accum[l] + accum[l + 64];
#pragma unroll
    for (int off = 32; off > 0; off >>= 1) v += __shfl_down(v, off, 64);
    if (l == 0) out[0] = 1.0f - v * (1.0f / N_TOTAL);
}

extern "C" void kernel_launch(void* const* d_in, const int* in_sizes, int n_in,
                              void* d_out, int out_size, void* d_ws, size_t ws_size,
                              hipStream_t stream) {
    const float* pred = (const float*)d_in[0];
    const float* targ = (const float*)d_in[1];
    float* out = (float*)d_out;
    float* ws  = (float*)d_ws;

    WB wb;
    {
        double gg[11], sum = 0.0;
        for (int k = 0; k < 11; ++k) {
            const double d = (double)(k - 5);
            gg[k] = exp(-d * d / 4.5);
            sum += gg[k];
        }
        double sbf = 0.0;
        for (int k = 0; k < 11; ++k) {
            union { float f; unsigned int u; } cv;
            cv.f = (float)(gg[k] / sum);
            const unsigned int r = (cv.u + 0x7fffu + ((cv.u >> 16) & 1u)) >> 16;
            wb.b[k] = (unsigned short)r;
            union { float f; unsigned int u; } bk;
            bk.u = r << 16;
            sbf += (double)bk.f;
        }
        const double s2 = sbf * sbf;       // acc = s2 * true value
        wb.c2 = (float)s2;
        wb.k1 = (float)(0.0001 * s2 * s2); // C1 in acc^2 units
        wb.k2 = (float)(0.0009 * s2 * s2); // C2 in acc^2 units
    }

    hipMemsetAsync(ws, 0, NACC * sizeof(float), stream);
    ssim_tiled<<<NBLOCKS, BLOCK, 0, stream>>>(pred, targ, ws, wb);
    ssim_finalize<<<1, 64, 0, stream>>>(ws, out);
}